// Round 4
// baseline (271.082 us; speedup 1.0000x reference)
//
#include <hip/hip_runtime.h>
#include <stdint.h>

#define KNN 16

typedef float vfloat4 __attribute__((ext_vector_type(4)));

// Map float to a uint32 whose unsigned order matches the float order
// (handles tiny negative dists from fp rounding).
__device__ __forceinline__ uint32_t fkey(float f) {
    uint32_t u = __float_as_uint(f);
    return (u & 0x80000000u) ? ~u : (u | 0x80000000u);
}

// FUSED: one wave per query does (a) exact KNN-16 via a wave-collective sorted
// top-16 distributed across lanes 0..15 (u64 keys fkey(dist)<<32|idx, so u64
// order == (dist asc, idx asc) == jax.lax.top_k stable order), then (b) the
// feature gather/diff/concat for its own 16 output rows — the indices never
// leave registers, no scratch, no second dispatch, no grid-wide dependency.
__global__ __launch_bounds__(256) void fused_kernel(
    const float* __restrict__ xyz_prev, const float* __restrict__ xyz_cur,
    const float* __restrict__ feat_prev, const float* __restrict__ feat_cur,
    float* __restrict__ out, int n_prev, int n_cur, int c4)
{
    const int lane = threadIdx.x & 63;
    const int q = blockIdx.x * 4 + (threadIdx.x >> 6);
    if (q >= n_cur) return;  // wave-uniform

    // ---------------- phase 1: exact KNN ----------------
    const float qx = xyz_cur[3 * q + 0];
    const float qy = xyz_cur[3 * q + 1];
    const float qz = xyz_cur[3 * q + 2];
    // Mirror reference fp32 op order (verified absmax 0 in R1-R3).
    // q2 is a per-query constant (cannot change the argsort).
    const float q2 = __fadd_rn(__fadd_rn(__fmul_rn(qx, qx), __fmul_rn(qy, qy)),
                               __fmul_rn(qz, qz));

    auto distkey = [&](int t) -> unsigned long long {
        const int r = (t << 6) + lane;
        if (r >= n_prev) return ~0ull;  // never beats any real key
        const float rx = xyz_prev[3 * r + 0];
        const float ry = xyz_prev[3 * r + 1];
        const float rz = xyz_prev[3 * r + 2];
        const float r2 = __fadd_rn(__fadd_rn(__fmul_rn(rx, rx), __fmul_rn(ry, ry)),
                                   __fmul_rn(rz, rz));
        const float cr = __fmaf_rn(rz, qz, __fmaf_rn(ry, qy, __fmul_rn(rx, qx)));
        const float dist = __fsub_rn(__fadd_rn(q2, r2), __fmul_rn(2.0f, cr));
        return ((unsigned long long)fkey(dist) << 32) | (uint32_t)r;
    };

    // Warmup: bitonic sort of the first 64 candidates across lanes (ascending);
    // lanes 0..15 seed the distributed top-16.
    unsigned long long v = distkey(0);
#pragma unroll
    for (int k = 2; k <= 64; k <<= 1) {
#pragma unroll
        for (int j = k >> 1; j > 0; j >>= 1) {
            const unsigned long long o = __shfl_xor(v, j, 64);
            const bool keepMin = (((lane & k) == 0) == ((lane & j) == 0));
            const bool omin = o < v;
            v = (keepMin == omin) ? o : v;  // keepMin ? min(v,o) : max(v,o)
        }
    }
    unsigned long long lkey = (lane < KNN) ? v : ~0ull;
    unsigned long long tau = __shfl(lkey, 15, 64);  // EXACT running 16th-best

    const int n_iter = (n_prev + 63) >> 6;  // wave-uniform trip count
    for (int t = 1; t < n_iter; ++t) {
        const unsigned long long key = distkey(t);
        unsigned long long mask = __ballot(key < tau);  // fires ~100x total
        while (mask) {  // wave-uniform
            const int b = (int)__builtin_ctzll(mask);
            mask &= mask - 1;
            const unsigned long long bk = __shfl(key, b, 64);
            if (bk < tau) {  // re-check: tau may have tightened this iteration
                const unsigned long long sh = __shfl_up(lkey, 1, 64);
                unsigned long long nk;
                if (lkey < bk) nk = lkey;                    // stays
                else nk = (lane == 0 || sh < bk) ? bk : sh;  // takes bk or shifts
                if (lane < KNN) lkey = nk;
                tau = __shfl(lkey, 15, 64);
            }
        }
    }

    // Broadcast the 16 winning indices to all lanes.
    int nb[KNN];
#pragma unroll
    for (int j = 0; j < KNN; ++j)
        nb[j] = (int)(__shfl(lkey, j, 64) & 0xffffffffu);

    // ---------------- phase 2: gather + combine ----------------
    // c4 = C/4 = 64: exactly one float4 per lane per half-row. 16 independent
    // gathered row-loads (L2-resident table), 32 nontemporal streaming stores
    // so the 134 MB write stream doesn't evict the 8 MB gather table.
    const vfloat4* pbase = (const vfloat4*)feat_prev;
    const vfloat4* crow  = (const vfloat4*)feat_cur + (size_t)q * c4;
    const int c8 = 2 * c4;

    for (int i = lane; i < c4; i += 64) {
        const vfloat4 c = crow[i];
        vfloat4 p[KNN];
#pragma unroll
        for (int j = 0; j < KNN; ++j)
            p[j] = pbase[(size_t)nb[j] * c4 + i];

#pragma unroll
        for (int j = 0; j < KNN; ++j) {
            vfloat4* orow = (vfloat4*)out + (size_t)(q * KNN + j) * c8;
            __builtin_nontemporal_store(p[j] - c, orow + i);
            __builtin_nontemporal_store(c, orow + c4 + i);
        }
    }
}

extern "C" void kernel_launch(void* const* d_in, const int* in_sizes, int n_in,
                              void* d_out, int out_size, void* d_ws, size_t ws_size,
                              hipStream_t stream) {
    const float* xyz_prev  = (const float*)d_in[0];
    const float* xyz_cur   = (const float*)d_in[1];
    const float* feat_prev = (const float*)d_in[2];
    const float* feat_cur  = (const float*)d_in[3];
    float* out = (float*)d_out;

    const int n_prev = in_sizes[0] / 3;
    const int n_cur  = in_sizes[1] / 3;
    const int C      = in_sizes[2] / n_prev;   // 256

    const int blocks = (n_cur + 3) / 4;        // 4 waves (queries) per block
    fused_kernel<<<blocks, 256, 0, stream>>>(xyz_prev, xyz_cur, feat_prev,
                                             feat_cur, out, n_prev, n_cur, C / 4);
}

// Round 6
// 208.070 us; speedup vs baseline: 1.3028x; 1.3028x over previous
//
#include <hip/hip_runtime.h>
#include <stdint.h>

#define KNN 16

typedef float vfloat4 __attribute__((ext_vector_type(4)));

// Map float to a uint32 whose unsigned order matches the float order
// (handles tiny negative dists from fp rounding).
__device__ __forceinline__ uint32_t fkey(float f) {
    uint32_t u = __float_as_uint(f);
    return (u & 0x80000000u) ? ~u : (u | 0x80000000u);
}

// Pack xyz_prev into (x, y, z, r2) float4 rows. r2 uses the exact fp32 op
// order of the reference (verified absmax 0 in R1-R4), so downstream
// distances are bit-identical to the verified R4 kernel.
__global__ __launch_bounds__(256) void prep_kernel(
    const float* __restrict__ xyz_prev, vfloat4* __restrict__ P, int n_prev)
{
    const int i = blockIdx.x * 256 + threadIdx.x;
    if (i >= n_prev) return;
    const float x = xyz_prev[3 * i + 0];
    const float y = xyz_prev[3 * i + 1];
    const float z = xyz_prev[3 * i + 2];
    const float r2 = __fadd_rn(__fadd_rn(__fmul_rn(x, x), __fmul_rn(y, y)),
                               __fmul_rn(z, z));
    vfloat4 v = {x, y, z, r2};
    P[i] = v;
}

// One wave per query. R4-verified control flow: per-iteration ballot + serial
// shuffle-insert into a wave-distributed sorted top-16 (lanes 0..15, u64 keys
// fkey(dist)<<32|idx == jax.lax.top_k stable order; tau = lane-15 key is the
// EXACT running global 16th-best). Only delta vs R4: candidates come from the
// packed P table, with 4 iterations' loads issued up front for memory-level
// parallelism. No batch gating, no goto (both R5-only, R5 failed).
__global__ __launch_bounds__(256) void knn_kernel(
    const vfloat4* __restrict__ P, const float* __restrict__ xyz_cur,
    int* __restrict__ knn_idx, int n_prev, int n_cur)
{
    const int lane = threadIdx.x & 63;
    const int q = blockIdx.x * 4 + (threadIdx.x >> 6);
    if (q >= n_cur) return;  // wave-uniform

    const float qx = xyz_cur[3 * q + 0];
    const float qy = xyz_cur[3 * q + 1];
    const float qz = xyz_cur[3 * q + 2];
    // q2 is a per-query constant (cannot change the argsort); same op order.
    const float q2 = __fadd_rn(__fadd_rn(__fmul_rn(qx, qx), __fmul_rn(qy, qy)),
                               __fmul_rn(qz, qz));

    // ---- warmup: bitonic sort of the first 64 candidates (ascending) ----
    unsigned long long v;
    {
        const int r = lane;
        const vfloat4 p = P[r < n_prev ? r : 0];
        const float cr = __fmaf_rn(p.z, qz, __fmaf_rn(p.y, qy, __fmul_rn(p.x, qx)));
        const float dist = __fsub_rn(__fadd_rn(q2, p.w), __fmul_rn(2.0f, cr));
        v = (r < n_prev)
            ? (((unsigned long long)fkey(dist) << 32) | (uint32_t)r)
            : ~0ull;
    }
#pragma unroll
    for (int k = 2; k <= 64; k <<= 1) {
#pragma unroll
        for (int j = k >> 1; j > 0; j >>= 1) {
            const unsigned long long o = __shfl_xor(v, j, 64);
            const bool keepMin = (((lane & k) == 0) == ((lane & j) == 0));
            const bool omin = o < v;
            v = (keepMin == omin) ? o : v;  // keepMin ? min(v,o) : max(v,o)
        }
    }
    unsigned long long lkey = (lane < KNN) ? v : ~0ull;
    unsigned long long tau = __shfl(lkey, 15, 64);  // EXACT running 16th-best

    const int n_iter = (n_prev + 63) >> 6;  // wave-uniform trip count
    int t = 1;
    // main: groups of 4 iterations, loads issued up front (4-deep MLP),
    // then each t processed with the verified per-t ballot+insert body.
    for (; t + 3 < n_iter; t += 4) {
        vfloat4 pv[4];
#pragma unroll
        for (int u = 0; u < 4; ++u) {
            const int r = ((t + u) << 6) + lane;
            pv[u] = P[r < n_prev ? r : 0];
        }
#pragma unroll
        for (int u = 0; u < 4; ++u) {
            const int r = ((t + u) << 6) + lane;
            const vfloat4 p = pv[u];
            const float cr = __fmaf_rn(p.z, qz, __fmaf_rn(p.y, qy, __fmul_rn(p.x, qx)));
            const float dist = __fsub_rn(__fadd_rn(q2, p.w), __fmul_rn(2.0f, cr));
            const unsigned long long key = (r < n_prev)
                ? (((unsigned long long)fkey(dist) << 32) | (uint32_t)r)
                : ~0ull;
            unsigned long long mask = __ballot(key < tau);
            while (mask) {  // wave-uniform
                const int b = (int)__builtin_ctzll(mask);
                mask &= mask - 1;
                const unsigned long long bk = __shfl(key, b, 64);
                if (bk < tau) {  // re-check: tau may have tightened
                    const unsigned long long sh = __shfl_up(lkey, 1, 64);
                    unsigned long long nk;
                    if (lkey < bk) nk = lkey;                    // stays
                    else nk = (lane == 0 || sh < bk) ? bk : sh;  // insert/shift
                    if (lane < KNN) lkey = nk;
                    tau = __shfl(lkey, 15, 64);
                }
            }
        }
    }
    // tail (runs only when n_prev % 256 != 0): identical single-t body
    for (; t < n_iter; ++t) {
        const int r = (t << 6) + lane;
        const vfloat4 p = P[r < n_prev ? r : 0];
        const float cr = __fmaf_rn(p.z, qz, __fmaf_rn(p.y, qy, __fmul_rn(p.x, qx)));
        const float dist = __fsub_rn(__fadd_rn(q2, p.w), __fmul_rn(2.0f, cr));
        const unsigned long long key = (r < n_prev)
            ? (((unsigned long long)fkey(dist) << 32) | (uint32_t)r)
            : ~0ull;
        unsigned long long mask = __ballot(key < tau);
        while (mask) {
            const int b = (int)__builtin_ctzll(mask);
            mask &= mask - 1;
            const unsigned long long bk = __shfl(key, b, 64);
            if (bk < tau) {
                const unsigned long long sh = __shfl_up(lkey, 1, 64);
                unsigned long long nk;
                if (lkey < bk) nk = lkey;
                else nk = (lane == 0 || sh < bk) ? bk : sh;
                if (lane < KNN) lkey = nk;
                tau = __shfl(lkey, 15, 64);
            }
        }
    }

    if (lane < KNN)
        knn_idx[q * KNN + lane] = (int)(lkey & 0xffffffffu);
}

// R3-VERIFIED combine, verbatim: one wave per query, load the shared cur row
// once, issue all 16 independent gathered prev-row float4 loads, then stream
// the 32 stores nontemporally (keep the 134 MB write stream from evicting the
// 8 MB gather table out of L2/LLC).
__global__ __launch_bounds__(256) void combine_kernel(
    const float* __restrict__ feat_prev, const float* __restrict__ feat_cur,
    const int* __restrict__ knn_idx, float* __restrict__ out,
    int n_cur, int c4)
{
    const int q = blockIdx.x * 4 + (threadIdx.x >> 6);
    const int lane = threadIdx.x & 63;
    if (q >= n_cur) return;

    int nb[KNN];
#pragma unroll
    for (int j = 0; j < KNN; ++j)
        nb[j] = knn_idx[q * KNN + j];

    const vfloat4* pbase = (const vfloat4*)feat_prev;
    const vfloat4* crow  = (const vfloat4*)feat_cur + (size_t)q * c4;
    const int c8 = 2 * c4;  // output row length in vfloat4

    for (int i = lane; i < c4; i += 64) {
        const vfloat4 c = crow[i];
        vfloat4 p[KNN];
#pragma unroll
        for (int j = 0; j < KNN; ++j)
            p[j] = pbase[(size_t)nb[j] * c4 + i];

#pragma unroll
        for (int j = 0; j < KNN; ++j) {
            vfloat4* orow = (vfloat4*)out + (size_t)(q * KNN + j) * c8;
            __builtin_nontemporal_store(p[j] - c, orow + i);
            __builtin_nontemporal_store(c, orow + c4 + i);
        }
    }
}

extern "C" void kernel_launch(void* const* d_in, const int* in_sizes, int n_in,
                              void* d_out, int out_size, void* d_ws, size_t ws_size,
                              hipStream_t stream) {
    const float* xyz_prev  = (const float*)d_in[0];
    const float* xyz_cur   = (const float*)d_in[1];
    const float* feat_prev = (const float*)d_in[2];
    const float* feat_cur  = (const float*)d_in[3];
    float* out = (float*)d_out;

    const int n_prev = in_sizes[0] / 3;
    const int n_cur  = in_sizes[1] / 3;
    const int C      = in_sizes[2] / n_prev;   // 256

    // d_ws layout: [0, 16*n_prev) packed (x,y,z,r2) table; then knn indices.
    vfloat4* P = (vfloat4*)d_ws;
    int* knn = (int*)((char*)d_ws + (size_t)n_prev * sizeof(vfloat4));

    prep_kernel<<<(n_prev + 255) / 256, 256, 0, stream>>>(xyz_prev, P, n_prev);

    const int knn_blocks = (n_cur + 3) / 4;    // 4 waves (queries) per block
    knn_kernel<<<knn_blocks, 256, 0, stream>>>(P, xyz_cur, knn, n_prev, n_cur);

    const int cmb_blocks = (n_cur + 3) / 4;    // 4 waves (queries) per block
    combine_kernel<<<cmb_blocks, 256, 0, stream>>>(feat_prev, feat_cur, knn, out,
                                                   n_cur, C / 4);
}

// Round 7
// 207.520 us; speedup vs baseline: 1.3063x; 1.0026x over previous
//
#include <hip/hip_runtime.h>
#include <stdint.h>

#define KNN 16

typedef float vfloat4 __attribute__((ext_vector_type(4)));

// Map float to a uint32 whose unsigned order matches the float order
// (handles tiny negative dists from fp rounding).
__device__ __forceinline__ uint32_t fkey(float f) {
    uint32_t u = __float_as_uint(f);
    return (u & 0x80000000u) ? ~u : (u | 0x80000000u);
}

// Pack xyz_prev into (x, y, z, r2) float4 rows. r2 uses the exact fp32 op
// order of the reference (verified absmax 0 in R1-R4, R6), so downstream
// distances are bit-identical.
__global__ __launch_bounds__(256) void prep_kernel(
    const float* __restrict__ xyz_prev, vfloat4* __restrict__ P, int n_prev)
{
    const int i = blockIdx.x * 256 + threadIdx.x;
    if (i >= n_prev) return;
    const float x = xyz_prev[3 * i + 0];
    const float y = xyz_prev[3 * i + 1];
    const float z = xyz_prev[3 * i + 2];
    const float r2 = __fadd_rn(__fadd_rn(__fmul_rn(x, x), __fmul_rn(y, y)),
                               __fmul_rn(z, z));
    vfloat4 v = {x, y, z, r2};
    P[i] = v;
}

// One wave per query. R6-verified control flow: per-iteration ballot + serial
// shuffle-insert into a wave-distributed sorted top-16 (lanes 0..15, u64 keys
// fkey(dist)<<32|idx == jax.lax.top_k stable order; tau = lane-15 key is the
// EXACT running global 16th-best). Only delta vs R6: load batch depth 4 -> 8
// (more memory-level parallelism; per-t processing bodies are byte-identical).
__global__ __launch_bounds__(256) void knn_kernel(
    const vfloat4* __restrict__ P, const float* __restrict__ xyz_cur,
    int* __restrict__ knn_idx, int n_prev, int n_cur)
{
    const int lane = threadIdx.x & 63;
    const int q = blockIdx.x * 4 + (threadIdx.x >> 6);
    if (q >= n_cur) return;  // wave-uniform

    const float qx = xyz_cur[3 * q + 0];
    const float qy = xyz_cur[3 * q + 1];
    const float qz = xyz_cur[3 * q + 2];
    // q2 is a per-query constant (cannot change the argsort); same op order.
    const float q2 = __fadd_rn(__fadd_rn(__fmul_rn(qx, qx), __fmul_rn(qy, qy)),
                               __fmul_rn(qz, qz));

    // ---- warmup: bitonic sort of the first 64 candidates (ascending) ----
    unsigned long long v;
    {
        const int r = lane;
        const vfloat4 p = P[r < n_prev ? r : 0];
        const float cr = __fmaf_rn(p.z, qz, __fmaf_rn(p.y, qy, __fmul_rn(p.x, qx)));
        const float dist = __fsub_rn(__fadd_rn(q2, p.w), __fmul_rn(2.0f, cr));
        v = (r < n_prev)
            ? (((unsigned long long)fkey(dist) << 32) | (uint32_t)r)
            : ~0ull;
    }
#pragma unroll
    for (int k = 2; k <= 64; k <<= 1) {
#pragma unroll
        for (int j = k >> 1; j > 0; j >>= 1) {
            const unsigned long long o = __shfl_xor(v, j, 64);
            const bool keepMin = (((lane & k) == 0) == ((lane & j) == 0));
            const bool omin = o < v;
            v = (keepMin == omin) ? o : v;  // keepMin ? min(v,o) : max(v,o)
        }
    }
    unsigned long long lkey = (lane < KNN) ? v : ~0ull;
    unsigned long long tau = __shfl(lkey, 15, 64);  // EXACT running 16th-best

    const int n_iter = (n_prev + 63) >> 6;  // wave-uniform trip count
    int t = 1;
    // main: groups of 8 iterations, loads issued up front (8-deep MLP),
    // then each t processed with the verified per-t ballot+insert body.
    for (; t + 7 < n_iter; t += 8) {
        vfloat4 pv[8];
#pragma unroll
        for (int u = 0; u < 8; ++u) {
            const int r = ((t + u) << 6) + lane;
            pv[u] = P[r < n_prev ? r : 0];
        }
#pragma unroll
        for (int u = 0; u < 8; ++u) {
            const int r = ((t + u) << 6) + lane;
            const vfloat4 p = pv[u];
            const float cr = __fmaf_rn(p.z, qz, __fmaf_rn(p.y, qy, __fmul_rn(p.x, qx)));
            const float dist = __fsub_rn(__fadd_rn(q2, p.w), __fmul_rn(2.0f, cr));
            const unsigned long long key = (r < n_prev)
                ? (((unsigned long long)fkey(dist) << 32) | (uint32_t)r)
                : ~0ull;
            unsigned long long mask = __ballot(key < tau);
            while (mask) {  // wave-uniform
                const int b = (int)__builtin_ctzll(mask);
                mask &= mask - 1;
                const unsigned long long bk = __shfl(key, b, 64);
                if (bk < tau) {  // re-check: tau may have tightened
                    const unsigned long long sh = __shfl_up(lkey, 1, 64);
                    unsigned long long nk;
                    if (lkey < bk) nk = lkey;                    // stays
                    else nk = (lane == 0 || sh < bk) ? bk : sh;  // insert/shift
                    if (lane < KNN) lkey = nk;
                    tau = __shfl(lkey, 15, 64);
                }
            }
        }
    }
    // tail: identical single-t body
    for (; t < n_iter; ++t) {
        const int r = (t << 6) + lane;
        const vfloat4 p = P[r < n_prev ? r : 0];
        const float cr = __fmaf_rn(p.z, qz, __fmaf_rn(p.y, qy, __fmul_rn(p.x, qx)));
        const float dist = __fsub_rn(__fadd_rn(q2, p.w), __fmul_rn(2.0f, cr));
        const unsigned long long key = (r < n_prev)
            ? (((unsigned long long)fkey(dist) << 32) | (uint32_t)r)
            : ~0ull;
        unsigned long long mask = __ballot(key < tau);
        while (mask) {
            const int b = (int)__builtin_ctzll(mask);
            mask &= mask - 1;
            const unsigned long long bk = __shfl(key, b, 64);
            if (bk < tau) {
                const unsigned long long sh = __shfl_up(lkey, 1, 64);
                unsigned long long nk;
                if (lkey < bk) nk = lkey;
                else nk = (lane == 0 || sh < bk) ? bk : sh;
                if (lane < KNN) lkey = nk;
                tau = __shfl(lkey, 15, 64);
            }
        }
    }

    if (lane < KNN)
        knn_idx[q * KNN + lane] = (int)(lkey & 0xffffffffu);
}

// One wave per (query, neighbor-group-of-4): 16K waves for 4x the TLP against
// gather latency. Per lane-iteration: one cur float4, 4 independent gathered
// prev rows, 8 nontemporal streaming stores (out is write-once; keep the
// 134 MB stream from evicting the 8 MB gather table out of L2/LLC).
// Coverage audit: w in [0, 4*n_cur) -> q = w>>2, jg = (w&3)*4; rows
// q*16 + jg + {0..3} — every output row exactly once.
__global__ __launch_bounds__(256) void combine_kernel(
    const float* __restrict__ feat_prev, const float* __restrict__ feat_cur,
    const int* __restrict__ knn_idx, float* __restrict__ out,
    int n_cur, int c4)
{
    const int w = blockIdx.x * 4 + (threadIdx.x >> 6);
    const int lane = threadIdx.x & 63;
    const int q = w >> 2;
    const int jg = (w & 3) * 4;
    if (q >= n_cur) return;

    int nb[4];
#pragma unroll
    for (int j = 0; j < 4; ++j)
        nb[j] = knn_idx[q * KNN + jg + j];

    const vfloat4* pbase = (const vfloat4*)feat_prev;
    const vfloat4* crow  = (const vfloat4*)feat_cur + (size_t)q * c4;
    const int c8 = 2 * c4;

    for (int i = lane; i < c4; i += 64) {
        const vfloat4 c = crow[i];
        vfloat4 p[4];
#pragma unroll
        for (int j = 0; j < 4; ++j)
            p[j] = pbase[(size_t)nb[j] * c4 + i];

#pragma unroll
        for (int j = 0; j < 4; ++j) {
            vfloat4* orow = (vfloat4*)out + (size_t)(q * KNN + jg + j) * c8;
            __builtin_nontemporal_store(p[j] - c, orow + i);
            __builtin_nontemporal_store(c, orow + c4 + i);
        }
    }
}

extern "C" void kernel_launch(void* const* d_in, const int* in_sizes, int n_in,
                              void* d_out, int out_size, void* d_ws, size_t ws_size,
                              hipStream_t stream) {
    const float* xyz_prev  = (const float*)d_in[0];
    const float* xyz_cur   = (const float*)d_in[1];
    const float* feat_prev = (const float*)d_in[2];
    const float* feat_cur  = (const float*)d_in[3];
    float* out = (float*)d_out;

    const int n_prev = in_sizes[0] / 3;
    const int n_cur  = in_sizes[1] / 3;
    const int C      = in_sizes[2] / n_prev;   // 256

    // d_ws layout: [0, 16*n_prev) packed (x,y,z,r2) table; then knn indices.
    vfloat4* P = (vfloat4*)d_ws;
    int* knn = (int*)((char*)d_ws + (size_t)n_prev * sizeof(vfloat4));

    prep_kernel<<<(n_prev + 255) / 256, 256, 0, stream>>>(xyz_prev, P, n_prev);

    const int knn_blocks = (n_cur + 3) / 4;    // 4 waves (queries) per block
    knn_kernel<<<knn_blocks, 256, 0, stream>>>(P, xyz_cur, knn, n_prev, n_cur);

    const int n_waves = n_cur * 4;             // 4 neighbor-rows per wave
    combine_kernel<<<(n_waves + 3) / 4, 256, 0, stream>>>(feat_prev, feat_cur,
                                                          knn, out, n_cur, C / 4);
}